// Round 3
// baseline (139.828 us; speedup 1.0000x reference)
//
#include <hip/hip_runtime.h>
#include <math.h>

#define BB 8
#define NN 256
#define DD 128

// ---------------- Kernel A: h = node@Wn+bn, ti = node@We1[:D]+be1, aj = node@We1[D:2D]
// 256 threads: d = tid&127, group g = tid>>7 handles rows 2g, 2g+1 of the block's 4 rows.
#define RT 4
__global__ __launch_bounds__(256) void prep_kernel(
    const float* __restrict__ node, const float* __restrict__ Wn,
    const float* __restrict__ bn, const float* __restrict__ We1,
    const float* __restrict__ be1, float* __restrict__ h,
    float* __restrict__ ti, float* __restrict__ aj)
{
    __shared__ float sx[RT][DD];
    int tid = threadIdx.x;
    int d = tid & 127;
    int g = tid >> 7;
    int row0 = blockIdx.x * RT;
    if (tid < 128) {                       // 128 float4s stage the 4 input rows
        int r = tid >> 5;
        int c = (tid & 31) << 2;
        *(float4*)&sx[r][c] = *(const float4*)&node[(row0 + r) * DD + c];
    }
    __syncthreads();
    float bnd = bn[d], be1d = be1[d];
    float acc_h0 = bnd, acc_h1 = bnd;
    float acc_i0 = be1d, acc_i1 = be1d;
    float acc_j0 = 0.f, acc_j1 = 0.f;
    int r0 = 2 * g, r1 = 2 * g + 1;
    for (int k = 0; k < DD; k += 4) {
        float4 x0 = *(const float4*)&sx[r0][k];
        float4 x1 = *(const float4*)&sx[r1][k];
        #pragma unroll
        for (int kk = 0; kk < 4; ++kk) {
            float w0 = Wn[(k + kk) * DD + d];
            float w1 = We1[(k + kk) * DD + d];
            float w2 = We1[(DD + k + kk) * DD + d];
            float a = (kk == 0) ? x0.x : (kk == 1) ? x0.y : (kk == 2) ? x0.z : x0.w;
            float c = (kk == 0) ? x1.x : (kk == 1) ? x1.y : (kk == 2) ? x1.z : x1.w;
            acc_h0 = fmaf(a, w0, acc_h0); acc_h1 = fmaf(c, w0, acc_h1);
            acc_i0 = fmaf(a, w1, acc_i0); acc_i1 = fmaf(c, w1, acc_i1);
            acc_j0 = fmaf(a, w2, acc_j0); acc_j1 = fmaf(c, w2, acc_j1);
        }
    }
    h [(row0 + r0) * DD + d] = acc_h0;  h [(row0 + r1) * DD + d] = acc_h1;
    ti[(row0 + r0) * DD + d] = acc_i0;  ti[(row0 + r1) * DD + d] = acc_i1;
    aj[(row0 + r0) * DD + d] = acc_j0;  aj[(row0 + r1) * DD + d] = acc_j1;
}

// ---------------- Kernel B (fused): edge scores + softmax (w stays in LDS) + msg=w@h
//                  + agg=relu(msg@Wa+ba) + residual + LayerNorm
#define IT 4
#define CH 32
#define STR (CH + 1)
__global__ __launch_bounds__(256) void edge_msg_kernel(
    const float* __restrict__ ti, const float* __restrict__ aj,
    const float* __restrict__ rel, const int* __restrict__ adj,
    const float* __restrict__ We1, const float* __restrict__ We2,
    const float* __restrict__ be2, const float* __restrict__ h,
    const float* __restrict__ Wa, const float* __restrict__ ba,
    const float* __restrict__ node, const float* __restrict__ gamma,
    const float* __restrict__ beta, float* __restrict__ out)
{
    __shared__ float smem[NN * STR];          // 8448 floats: aj-chunks, later s_w/s_m
    __shared__ float s_red[IT][4];
    __shared__ float s_red2[IT][2][2];
    int tid = threadIdx.x;
    int b  = blockIdx.x / (NN / IT);
    int i0 = (blockIdx.x % (NN / IT)) * IT;
    int j = tid;

    // ---- Phase 1: edge scores for rows i0..i0+3, this thread owns column j
    const float2* rel2 = (const float2*)rel;
    float rx[IT], ry[IT], dist[IT];
    int msk[IT];
    #pragma unroll
    for (int r = 0; r < IT; ++r) {
        float2 rp = rel2[(b * NN + i0 + r) * NN + j];
        rx[r] = rp.x; ry[r] = rp.y;
        dist[r] = sqrtf(rp.x * rp.x + rp.y * rp.y);
        msk[r] = adj[(b * NN + i0 + r) * NN + j];
    }
    float be2v = be2[0];
    float score[IT];
    #pragma unroll
    for (int r = 0; r < IT; ++r) score[r] = be2v;

    const float* ti_b = ti + ((long)b * NN + i0) * DD;
    const float* w0p = We1 + (2 * DD + 0) * DD;
    const float* w1p = We1 + (2 * DD + 1) * DD;
    const float* w2p = We1 + (2 * DD + 2) * DD;

    for (int dc = 0; dc < DD; dc += CH) {
        __syncthreads();
        #pragma unroll
        for (int it = 0; it < 8; ++it) {
            int idx = tid + it * 256;            // 0..2047 float4s
            int rrow = idx >> 3;
            int c4 = (idx & 7) << 2;
            float4 v = *(const float4*)(aj + (b * NN + rrow) * DD + dc + c4);
            float* p = &smem[rrow * STR + c4];
            p[0] = v.x; p[1] = v.y; p[2] = v.z; p[3] = v.w;
        }
        __syncthreads();
        #pragma unroll 4
        for (int d = 0; d < CH; d += 2) {
            int dd = dc + d;
            float a0 = smem[j * STR + d];
            float a1 = smem[j * STR + d + 1];
            float2 w0 = *(const float2*)(w0p + dd);
            float2 w1 = *(const float2*)(w1p + dd);
            float2 w2 = *(const float2*)(w2p + dd);
            float2 e2 = *(const float2*)(We2 + dd);
            #pragma unroll
            for (int r = 0; r < IT; ++r) {
                float2 t = *(const float2*)(ti_b + r * DD + dd);
                float v0 = fmaf(rx[r], w0.x, t.x + a0);
                v0 = fmaf(ry[r], w1.x, v0);
                v0 = fmaf(dist[r], w2.x, v0);
                v0 = fmaxf(v0, 0.f);
                float v1 = fmaf(rx[r], w0.y, t.y + a1);
                v1 = fmaf(ry[r], w1.y, v1);
                v1 = fmaf(dist[r], w2.y, v1);
                v1 = fmaxf(v1, 0.f);
                score[r] = fmaf(v0, e2.x, score[r]);
                score[r] = fmaf(v1, e2.y, score[r]);
            }
        }
    }
    #pragma unroll
    for (int r = 0; r < IT; ++r) if (msk[r] == 0) score[r] = -3.0e38f;

    // ---- Phase 2: masked softmax across j (256 threads = 4 waves)
    int wave = tid >> 6, lane = tid & 63;
    float M[IT], e[IT], wv[IT];
    #pragma unroll
    for (int r = 0; r < IT; ++r) {
        float m = score[r];
        for (int off = 32; off > 0; off >>= 1) m = fmaxf(m, __shfl_xor(m, off));
        if (lane == 0) s_red[r][wave] = m;
    }
    __syncthreads();       // also: last reader of smem-as-aj is done before this point
    #pragma unroll
    for (int r = 0; r < IT; ++r)
        M[r] = fmaxf(fmaxf(s_red[r][0], s_red[r][1]), fmaxf(s_red[r][2], s_red[r][3]));
    #pragma unroll
    for (int r = 0; r < IT; ++r) e[r] = (msk[r] == 0) ? 0.f : __expf(score[r] - M[r]);
    __syncthreads();
    #pragma unroll
    for (int r = 0; r < IT; ++r) {
        float s = e[r];
        for (int off = 32; off > 0; off >>= 1) s += __shfl_xor(s, off);
        if (lane == 0) s_red[r][wave] = s;
    }
    __syncthreads();
    float* s_w = smem;                 // 4*256 floats (aliases dead aj region)
    float* s_m = smem + IT * NN;       // 4*128 floats
    #pragma unroll
    for (int r = 0; r < IT; ++r) {
        float S = s_red[r][0] + s_red[r][1] + s_red[r][2] + s_red[r][3];
        wv[r] = e[r] * __builtin_amdgcn_rcpf(S);
        s_w[r * NN + j] = wv[r];
    }
    __syncthreads();

    // ---- Phase 3: msg = w @ h  (256 threads: d = tid&127, group g = tid>>7 owns rows 2g,2g+1)
    int d = tid & 127;
    int g = tid >> 7;
    int r0 = 2 * g, r1 = 2 * g + 1;
    const float* hb = h + ((long)b * NN) * DD;
    float acc0 = 0.f, acc1 = 0.f;
    for (int jj = 0; jj < NN; jj += 4) {
        float4 w0v = *(const float4*)&s_w[r0 * NN + jj];
        float4 w1v = *(const float4*)&s_w[r1 * NN + jj];
        float h0 = hb[(jj + 0) * DD + d];
        float h1 = hb[(jj + 1) * DD + d];
        float h2 = hb[(jj + 2) * DD + d];
        float h3 = hb[(jj + 3) * DD + d];
        acc0 = fmaf(w0v.x, h0, acc0); acc1 = fmaf(w1v.x, h0, acc1);
        acc0 = fmaf(w0v.y, h1, acc0); acc1 = fmaf(w1v.y, h1, acc1);
        acc0 = fmaf(w0v.z, h2, acc0); acc1 = fmaf(w1v.z, h2, acc1);
        acc0 = fmaf(w0v.w, h3, acc0); acc1 = fmaf(w1v.w, h3, acc1);
    }
    __syncthreads();                   // s_w reads done before s_m overwrites? (s_m is disjoint region, but keep ordering tight)
    s_m[r0 * DD + d] = acc0;
    s_m[r1 * DD + d] = acc1;
    __syncthreads();

    // ---- Phase 4: agg = relu(msg@Wa+ba), residual, LayerNorm
    float bad = ba[d];
    float agg0 = bad, agg1 = bad;
    for (int k = 0; k < DD; k += 4) {
        float4 m0 = *(const float4*)&s_m[r0 * DD + k];
        float4 m1 = *(const float4*)&s_m[r1 * DD + k];
        float wa0 = Wa[(k + 0) * DD + d];
        float wa1 = Wa[(k + 1) * DD + d];
        float wa2 = Wa[(k + 2) * DD + d];
        float wa3 = Wa[(k + 3) * DD + d];
        agg0 = fmaf(m0.x, wa0, agg0); agg1 = fmaf(m1.x, wa0, agg1);
        agg0 = fmaf(m0.y, wa1, agg0); agg1 = fmaf(m1.y, wa1, agg1);
        agg0 = fmaf(m0.z, wa2, agg0); agg1 = fmaf(m1.z, wa2, agg1);
        agg0 = fmaf(m0.w, wa3, agg0); agg1 = fmaf(m1.w, wa3, agg1);
    }
    int wv_id = (tid >> 6) & 1;        // wave within group
    float gam = gamma[d], bet = beta[d];
    float x0 = node[(b * NN + i0 + r0) * DD + d] + fmaxf(agg0, 0.f);
    float x1 = node[(b * NN + i0 + r1) * DD + d] + fmaxf(agg1, 0.f);
    {
        float s1 = x0, s2 = x0 * x0;
        for (int off = 32; off > 0; off >>= 1) {
            s1 += __shfl_xor(s1, off);
            s2 += __shfl_xor(s2, off);
        }
        if (lane == 0) { s_red2[r0][wv_id][0] = s1; s_red2[r0][wv_id][1] = s2; }
    }
    {
        float s1 = x1, s2 = x1 * x1;
        for (int off = 32; off > 0; off >>= 1) {
            s1 += __shfl_xor(s1, off);
            s2 += __shfl_xor(s2, off);
        }
        if (lane == 0) { s_red2[r1][wv_id][0] = s1; s_red2[r1][wv_id][1] = s2; }
    }
    __syncthreads();
    {
        float s1 = s_red2[r0][0][0] + s_red2[r0][1][0];
        float s2 = s_red2[r0][0][1] + s_red2[r0][1][1];
        float mu  = s1 * (1.0f / DD);
        float var = s2 * (1.0f / DD) - mu * mu;
        float inv = rsqrtf(var + 1e-5f);
        out[(b * NN + i0 + r0) * DD + d] = (x0 - mu) * inv * gam + bet;
    }
    {
        float s1 = s_red2[r1][0][0] + s_red2[r1][1][0];
        float s2 = s_red2[r1][0][1] + s_red2[r1][1][1];
        float mu  = s1 * (1.0f / DD);
        float var = s2 * (1.0f / DD) - mu * mu;
        float inv = rsqrtf(var + 1e-5f);
        out[(b * NN + i0 + r1) * DD + d] = (x1 - mu) * inv * gam + bet;
    }
}

extern "C" void kernel_launch(void* const* d_in, const int* in_sizes, int n_in,
                              void* d_out, int out_size, void* d_ws, size_t ws_size,
                              hipStream_t stream) {
    const float* node = (const float*)d_in[0];
    const int*   adj  = (const int*)d_in[1];
    const float* rel  = (const float*)d_in[2];
    const float* Wn   = (const float*)d_in[3];
    const float* bn   = (const float*)d_in[4];
    const float* We1  = (const float*)d_in[5];
    const float* be1  = (const float*)d_in[6];
    const float* We2  = (const float*)d_in[7];
    const float* be2  = (const float*)d_in[8];
    const float* Wa   = (const float*)d_in[9];
    const float* ba   = (const float*)d_in[10];
    const float* gamma = (const float*)d_in[11];
    const float* beta  = (const float*)d_in[12];
    float* out = (float*)d_out;

    float* ws  = (float*)d_ws;
    const int ROWS = BB * NN * DD;          // 262144
    float* h   = ws;
    float* ti  = ws + ROWS;
    float* aj  = ws + 2 * ROWS;

    prep_kernel<<<BB * NN / RT, 256, 0, stream>>>(node, Wn, bn, We1, be1, h, ti, aj);
    edge_msg_kernel<<<BB * NN / IT, 256, 0, stream>>>(ti, aj, rel, adj, We1, We2, be2,
                                                      h, Wa, ba, node, gamma, beta, out);
}

// Round 4
// 132.347 us; speedup vs baseline: 1.0565x; 1.0565x over previous
//
#include <hip/hip_runtime.h>
#include <math.h>

#define BB 8
#define NN 256
#define DD 128

// ---------------- Kernel A: h = node@Wn+bn, ti = node@We1[:D]+be1, aj = node@We1[D:2D]
// 512 threads; 8 rows/block; thread owns row r = tid>>6, d-cols {2c, 2c+1}, c = tid&63.
#define PR 8
__global__ __launch_bounds__(512) void prep_kernel(
    const float* __restrict__ node, const float* __restrict__ Wn,
    const float* __restrict__ bn, const float* __restrict__ We1,
    const float* __restrict__ be1, float* __restrict__ h,
    float* __restrict__ ti, float* __restrict__ aj)
{
    __shared__ float sx[PR][DD];
    int tid = threadIdx.x;
    int c = tid & 63;
    int r = tid >> 6;
    int d0 = 2 * c;
    int row0 = blockIdx.x * PR;
    if (tid < 256) {                       // 256 float4s stage the 8 input rows
        int rr = tid >> 5;
        int cc = (tid & 31) << 2;
        *(float4*)&sx[rr][cc] = *(const float4*)&node[(row0 + rr) * DD + cc];
    }
    __syncthreads();
    float2 bn2  = *(const float2*)&bn[d0];
    float2 be12 = *(const float2*)&be1[d0];
    float ah0 = bn2.x, ah1 = bn2.y;
    float ai0 = be12.x, ai1 = be12.y;
    float aj0 = 0.f, aj1 = 0.f;
    for (int k = 0; k < DD; k += 4) {
        float4 x = *(const float4*)&sx[r][k];
        #pragma unroll
        for (int kk = 0; kk < 4; ++kk) {
            float2 w0 = *(const float2*)&Wn[(k + kk) * DD + d0];
            float2 w1 = *(const float2*)&We1[(k + kk) * DD + d0];
            float2 w2 = *(const float2*)&We1[(DD + k + kk) * DD + d0];
            float xv = (kk == 0) ? x.x : (kk == 1) ? x.y : (kk == 2) ? x.z : x.w;
            ah0 = fmaf(xv, w0.x, ah0); ah1 = fmaf(xv, w0.y, ah1);
            ai0 = fmaf(xv, w1.x, ai0); ai1 = fmaf(xv, w1.y, ai1);
            aj0 = fmaf(xv, w2.x, aj0); aj1 = fmaf(xv, w2.y, aj1);
        }
    }
    long o = (long)(row0 + r) * DD + d0;
    *(float2*)&h [o] = make_float2(ah0, ah1);
    *(float2*)&ti[o] = make_float2(ai0, ai1);
    *(float2*)&aj[o] = make_float2(aj0, aj1);
}

// ---------------- Kernel B (fused): edge scores + softmax (w in LDS) + msg=w@h
//                  + agg=relu(msg@Wa+ba) + residual + LayerNorm
// 512 threads = 2 halves; half g owns rows {2g, 2g+1} of the block's 4 rows; j = tid&255.
#define IT 4
#define CH 32
#define STR (CH + 1)
__global__ __launch_bounds__(512, 4) void edge_msg_kernel(
    const float* __restrict__ ti, const float* __restrict__ aj,
    const float* __restrict__ rel, const int* __restrict__ adj,
    const float* __restrict__ We1, const float* __restrict__ We2,
    const float* __restrict__ be2, const float* __restrict__ h,
    const float* __restrict__ Wa, const float* __restrict__ ba,
    const float* __restrict__ node, const float* __restrict__ gamma,
    const float* __restrict__ beta, float* __restrict__ out)
{
    __shared__ float s_aj[NN * STR];          // 8448 floats; later aliased by s_w/s_m
    __shared__ float s_ti[IT * DD];           // 512
    __shared__ float s_wt[4 * DD];            // w0,w1,w2,We2 rows
    __shared__ float s_red[IT][4];
    __shared__ float s_red2[IT][2][2];

    int tid = threadIdx.x;
    int b  = blockIdx.x / (NN / IT);
    int i0 = (blockIdx.x % (NN / IT)) * IT;
    int g  = tid >> 8;                        // half: 0/1
    int j  = tid & 255;
    int r0 = 2 * g, r1 = 2 * g + 1;

    // one-time uniform staging: ti rows + rel-weight rows + We2
    if (tid < 128) {
        int rr = tid >> 5, cc = (tid & 31) << 2;
        *(float4*)&s_ti[rr * DD + cc] = *(const float4*)&ti[(long)(b * NN + i0 + rr) * DD + cc];
    } else if (tid < 224) {
        int t = tid - 128;                    // 0..95 -> 3 rows
        int rr = t >> 5, cc = (t & 31) << 2;
        *(float4*)&s_wt[rr * DD + cc] = *(const float4*)&We1[(2 * DD + rr) * DD + cc];
    } else if (tid < 256) {
        int cc = (tid - 224) << 2;
        *(float4*)&s_wt[3 * DD + cc] = *(const float4*)&We2[cc];
    }

    const float2* rel2 = (const float2*)rel;
    float2 rp0 = rel2[(b * NN + i0 + r0) * NN + j];
    float2 rp1 = rel2[(b * NN + i0 + r1) * NN + j];
    float rx0 = rp0.x, ry0 = rp0.y, ds0 = sqrtf(rp0.x * rp0.x + rp0.y * rp0.y);
    float rx1 = rp1.x, ry1 = rp1.y, ds1 = sqrtf(rp1.x * rp1.x + rp1.y * rp1.y);
    int m0 = adj[(b * NN + i0 + r0) * NN + j];
    int m1 = adj[(b * NN + i0 + r1) * NN + j];
    float be2v = be2[0];
    float sc0 = be2v, sc1 = be2v;

    // ---- Phase 1: scores
    for (int dc = 0; dc < DD; dc += CH) {
        __syncthreads();
        #pragma unroll
        for (int it = 0; it < 4; ++it) {
            int idx = tid + it * 512;          // 0..2047 float4s
            int rrow = idx >> 3;
            int c4 = (idx & 7) << 2;
            float4 v = *(const float4*)(aj + (long)(b * NN + rrow) * DD + dc + c4);
            float* p = &s_aj[rrow * STR + c4];
            p[0] = v.x; p[1] = v.y; p[2] = v.z; p[3] = v.w;
        }
        __syncthreads();
        #pragma unroll
        for (int d = 0; d < CH; d += 4) {
            float4 a  = *(const float4*)&s_aj[j * STR + d];
            float4 t0 = *(const float4*)&s_ti[r0 * DD + dc + d];
            float4 t1 = *(const float4*)&s_ti[r1 * DD + dc + d];
            float4 w0 = *(const float4*)&s_wt[0 * DD + dc + d];
            float4 w1 = *(const float4*)&s_wt[1 * DD + dc + d];
            float4 w2 = *(const float4*)&s_wt[2 * DD + dc + d];
            float4 e2 = *(const float4*)&s_wt[3 * DD + dc + d];
            {
                float v0 = fmaf(rx0, w0.x, t0.x + a.x); v0 = fmaf(ry0, w1.x, v0); v0 = fmaf(ds0, w2.x, v0);
                float v1 = fmaf(rx1, w0.x, t1.x + a.x); v1 = fmaf(ry1, w1.x, v1); v1 = fmaf(ds1, w2.x, v1);
                sc0 = fmaf(fmaxf(v0, 0.f), e2.x, sc0); sc1 = fmaf(fmaxf(v1, 0.f), e2.x, sc1);
            }
            {
                float v0 = fmaf(rx0, w0.y, t0.y + a.y); v0 = fmaf(ry0, w1.y, v0); v0 = fmaf(ds0, w2.y, v0);
                float v1 = fmaf(rx1, w0.y, t1.y + a.y); v1 = fmaf(ry1, w1.y, v1); v1 = fmaf(ds1, w2.y, v1);
                sc0 = fmaf(fmaxf(v0, 0.f), e2.y, sc0); sc1 = fmaf(fmaxf(v1, 0.f), e2.y, sc1);
            }
            {
                float v0 = fmaf(rx0, w0.z, t0.z + a.z); v0 = fmaf(ry0, w1.z, v0); v0 = fmaf(ds0, w2.z, v0);
                float v1 = fmaf(rx1, w0.z, t1.z + a.z); v1 = fmaf(ry1, w1.z, v1); v1 = fmaf(ds1, w2.z, v1);
                sc0 = fmaf(fmaxf(v0, 0.f), e2.z, sc0); sc1 = fmaf(fmaxf(v1, 0.f), e2.z, sc1);
            }
            {
                float v0 = fmaf(rx0, w0.w, t0.w + a.w); v0 = fmaf(ry0, w1.w, v0); v0 = fmaf(ds0, w2.w, v0);
                float v1 = fmaf(rx1, w0.w, t1.w + a.w); v1 = fmaf(ry1, w1.w, v1); v1 = fmaf(ds1, w2.w, v1);
                sc0 = fmaf(fmaxf(v0, 0.f), e2.w, sc0); sc1 = fmaf(fmaxf(v1, 0.f), e2.w, sc1);
            }
        }
    }
    if (m0 == 0) sc0 = -3.0e38f;
    if (m1 == 0) sc1 = -3.0e38f;

    // ---- Phase 2: masked softmax across j within each 4-wave half
    int wig = (tid >> 6) & 3;
    int lane = tid & 63;
    {
        float mm0 = sc0, mm1 = sc1;
        for (int off = 32; off > 0; off >>= 1) {
            mm0 = fmaxf(mm0, __shfl_xor(mm0, off));
            mm1 = fmaxf(mm1, __shfl_xor(mm1, off));
        }
        if (lane == 0) { s_red[r0][wig] = mm0; s_red[r1][wig] = mm1; }
    }
    __syncthreads();                           // also: all s_aj reads complete
    float M0 = fmaxf(fmaxf(s_red[r0][0], s_red[r0][1]), fmaxf(s_red[r0][2], s_red[r0][3]));
    float M1 = fmaxf(fmaxf(s_red[r1][0], s_red[r1][1]), fmaxf(s_red[r1][2], s_red[r1][3]));
    float e0 = (m0 == 0) ? 0.f : __expf(sc0 - M0);
    float e1 = (m1 == 0) ? 0.f : __expf(sc1 - M1);
    __syncthreads();
    {
        float ss0 = e0, ss1 = e1;
        for (int off = 32; off > 0; off >>= 1) {
            ss0 += __shfl_xor(ss0, off);
            ss1 += __shfl_xor(ss1, off);
        }
        if (lane == 0) { s_red[r0][wig] = ss0; s_red[r1][wig] = ss1; }
    }
    __syncthreads();
    float* s_w = s_aj;                         // 4*256 floats (aj dead)
    float* s_m = s_aj + IT * NN;               // 4*128 floats
    {
        float S0 = s_red[r0][0] + s_red[r0][1] + s_red[r0][2] + s_red[r0][3];
        float S1 = s_red[r1][0] + s_red[r1][1] + s_red[r1][2] + s_red[r1][3];
        s_w[r0 * NN + j] = e0 * __builtin_amdgcn_rcpf(S0);
        s_w[r1 * NN + j] = e1 * __builtin_amdgcn_rcpf(S1);
    }
    __syncthreads();

    // ---- Phase 3: msg = w @ h   (row = tid>>7 in [0,4), d = tid&127)
    int d = tid & 127;
    int row = tid >> 7;
    const float* hb = h + (long)b * NN * DD;
    float acc = 0.f;
    for (int jj = 0; jj < NN; jj += 4) {
        float4 wv = *(const float4*)&s_w[row * NN + jj];
        float h0 = hb[(jj + 0) * DD + d];
        float h1 = hb[(jj + 1) * DD + d];
        float h2 = hb[(jj + 2) * DD + d];
        float h3 = hb[(jj + 3) * DD + d];
        acc = fmaf(wv.x, h0, acc);
        acc = fmaf(wv.y, h1, acc);
        acc = fmaf(wv.z, h2, acc);
        acc = fmaf(wv.w, h3, acc);
    }
    s_m[row * DD + d] = acc;                   // disjoint from s_w region
    __syncthreads();

    // ---- Phase 4: agg = relu(msg@Wa+ba), residual, LayerNorm
    float agg = ba[d];
    for (int k = 0; k < DD; k += 4) {
        float4 mv = *(const float4*)&s_m[row * DD + k];
        float wa0 = Wa[(k + 0) * DD + d];
        float wa1 = Wa[(k + 1) * DD + d];
        float wa2 = Wa[(k + 2) * DD + d];
        float wa3 = Wa[(k + 3) * DD + d];
        agg = fmaf(mv.x, wa0, agg);
        agg = fmaf(mv.y, wa1, agg);
        agg = fmaf(mv.z, wa2, agg);
        agg = fmaf(mv.w, wa3, agg);
    }
    float x = node[(long)(b * NN + i0 + row) * DD + d] + fmaxf(agg, 0.f);
    int w2id = (tid >> 6) & 1;
    {
        float s1 = x, s2 = x * x;
        for (int off = 32; off > 0; off >>= 1) {
            s1 += __shfl_xor(s1, off);
            s2 += __shfl_xor(s2, off);
        }
        if (lane == 0) { s_red2[row][w2id][0] = s1; s_red2[row][w2id][1] = s2; }
    }
    __syncthreads();
    {
        float s1 = s_red2[row][0][0] + s_red2[row][1][0];
        float s2 = s_red2[row][0][1] + s_red2[row][1][1];
        float mu  = s1 * (1.0f / DD);
        float var = s2 * (1.0f / DD) - mu * mu;
        float inv = rsqrtf(var + 1e-5f);
        out[(long)(b * NN + i0 + row) * DD + d] = (x - mu) * inv * gamma[d] + beta[d];
    }
}

extern "C" void kernel_launch(void* const* d_in, const int* in_sizes, int n_in,
                              void* d_out, int out_size, void* d_ws, size_t ws_size,
                              hipStream_t stream) {
    const float* node = (const float*)d_in[0];
    const int*   adj  = (const int*)d_in[1];
    const float* rel  = (const float*)d_in[2];
    const float* Wn   = (const float*)d_in[3];
    const float* bn   = (const float*)d_in[4];
    const float* We1  = (const float*)d_in[5];
    const float* be1  = (const float*)d_in[6];
    const float* We2  = (const float*)d_in[7];
    const float* be2  = (const float*)d_in[8];
    const float* Wa   = (const float*)d_in[9];
    const float* ba   = (const float*)d_in[10];
    const float* gamma = (const float*)d_in[11];
    const float* beta  = (const float*)d_in[12];
    float* out = (float*)d_out;

    float* ws  = (float*)d_ws;
    const int ROWS = BB * NN * DD;          // 262144
    float* h   = ws;
    float* ti  = ws + ROWS;
    float* aj  = ws + 2 * ROWS;

    prep_kernel<<<BB * NN / PR, 512, 0, stream>>>(node, Wn, bn, We1, be1, h, ti, aj);
    edge_msg_kernel<<<BB * NN / IT, 512, 0, stream>>>(ti, aj, rel, adj, We1, We2, be2,
                                                      h, Wa, ba, node, gamma, beta, out);
}

// Round 5
// 122.001 us; speedup vs baseline: 1.1461x; 1.0848x over previous
//
#include <hip/hip_runtime.h>
#include <math.h>

#define BB 8
#define NN 256
#define DD 128

// ---------------- Kernel A: h = node@Wn+bn, ti = node@We1[:D]+be1, aj = node@We1[D:2D]
// 256 threads, 4 rows/block. Thread: cp=tid&63 (d-pair), rp=(tid>>6)&1 (row-pair), ks=tid>>7 (k-half).
#define PR 4
__global__ __launch_bounds__(256) void prep_kernel(
    const float* __restrict__ node, const float* __restrict__ Wn,
    const float* __restrict__ bn, const float* __restrict__ We1,
    const float* __restrict__ be1, float* __restrict__ h,
    float* __restrict__ ti, float* __restrict__ aj)
{
    __shared__ __align__(16) float sx[PR * DD];
    __shared__ float s_acc[12 * 128];
    int tid = threadIdx.x;
    int cp = tid & 63;
    int rp = (tid >> 6) & 1;
    int ks = tid >> 7;
    int row0 = blockIdx.x * PR;
    if (tid < 128) {
        int rr = tid >> 5, cc = (tid & 31) << 2;
        *(float4*)&sx[rr * DD + cc] = *(const float4*)&node[(size_t)(row0 + rr) * DD + cc];
    }
    __syncthreads();
    int d0 = cp << 1;
    int ra = rp << 1, rb = ra | 1;
    float ah[2] = {0.f, 0.f}, ai[2] = {0.f, 0.f}, ajc[2] = {0.f, 0.f};
    float bh[2] = {0.f, 0.f}, bi[2] = {0.f, 0.f}, bjc[2] = {0.f, 0.f};
    int k0 = ks << 6;
    for (int k = k0; k < k0 + 64; k += 4) {
        float4 xa = *(const float4*)&sx[ra * DD + k];
        float4 xb = *(const float4*)&sx[rb * DD + k];
        #pragma unroll
        for (int kk = 0; kk < 4; ++kk) {
            float2 w0 = *(const float2*)&Wn [(size_t)(k + kk) * DD + d0];
            float2 w1 = *(const float2*)&We1[(size_t)(k + kk) * DD + d0];
            float2 w2 = *(const float2*)&We1[(size_t)(DD + k + kk) * DD + d0];
            float xav = (kk == 0) ? xa.x : (kk == 1) ? xa.y : (kk == 2) ? xa.z : xa.w;
            float xbv = (kk == 0) ? xb.x : (kk == 1) ? xb.y : (kk == 2) ? xb.z : xb.w;
            ah[0] = fmaf(xav, w0.x, ah[0]); ah[1] = fmaf(xav, w0.y, ah[1]);
            ai[0] = fmaf(xav, w1.x, ai[0]); ai[1] = fmaf(xav, w1.y, ai[1]);
            ajc[0] = fmaf(xav, w2.x, ajc[0]); ajc[1] = fmaf(xav, w2.y, ajc[1]);
            bh[0] = fmaf(xbv, w0.x, bh[0]); bh[1] = fmaf(xbv, w0.y, bh[1]);
            bi[0] = fmaf(xbv, w1.x, bi[0]); bi[1] = fmaf(xbv, w1.y, bi[1]);
            bjc[0] = fmaf(xbv, w2.x, bjc[0]); bjc[1] = fmaf(xbv, w2.y, bjc[1]);
        }
    }
    int p = (rp << 6) | cp;
    if (ks == 1) {
        s_acc[0 * 128 + p] = ah[0];  s_acc[1 * 128 + p] = ah[1];
        s_acc[2 * 128 + p] = ai[0];  s_acc[3 * 128 + p] = ai[1];
        s_acc[4 * 128 + p] = ajc[0]; s_acc[5 * 128 + p] = ajc[1];
        s_acc[6 * 128 + p] = bh[0];  s_acc[7 * 128 + p] = bh[1];
        s_acc[8 * 128 + p] = bi[0];  s_acc[9 * 128 + p] = bi[1];
        s_acc[10 * 128 + p] = bjc[0]; s_acc[11 * 128 + p] = bjc[1];
    }
    __syncthreads();
    if (ks == 0) {
        float2 bn2  = *(const float2*)&bn[d0];
        float2 be12 = *(const float2*)&be1[d0];
        ah[0] += s_acc[0 * 128 + p] + bn2.x;  ah[1] += s_acc[1 * 128 + p] + bn2.y;
        ai[0] += s_acc[2 * 128 + p] + be12.x; ai[1] += s_acc[3 * 128 + p] + be12.y;
        ajc[0] += s_acc[4 * 128 + p];         ajc[1] += s_acc[5 * 128 + p];
        bh[0] += s_acc[6 * 128 + p] + bn2.x;  bh[1] += s_acc[7 * 128 + p] + bn2.y;
        bi[0] += s_acc[8 * 128 + p] + be12.x; bi[1] += s_acc[9 * 128 + p] + be12.y;
        bjc[0] += s_acc[10 * 128 + p];        bjc[1] += s_acc[11 * 128 + p];
        size_t oa = (size_t)(row0 + ra) * DD + d0;
        size_t ob = (size_t)(row0 + rb) * DD + d0;
        *(float2*)&h [oa] = make_float2(ah[0], ah[1]);
        *(float2*)&ti[oa] = make_float2(ai[0], ai[1]);
        *(float2*)&aj[oa] = make_float2(ajc[0], ajc[1]);
        *(float2*)&h [ob] = make_float2(bh[0], bh[1]);
        *(float2*)&ti[ob] = make_float2(bi[0], bi[1]);
        *(float2*)&aj[ob] = make_float2(bjc[0], bjc[1]);
    }
}

// ---------------- Kernel B (fused): scores + softmax + msg=w@h + relu(msg@Wa+ba) + residual + LN
// 256 threads, IT=2 rows/block, grid = B*N/2 = 1024.
#define IT 2
__global__ __launch_bounds__(256, 4) void edge_kernel(
    const float* __restrict__ ti, const float* __restrict__ ajp,
    const float* __restrict__ rel, const int* __restrict__ adj,
    const float* __restrict__ We1, const float* __restrict__ We2,
    const float* __restrict__ be2, const float* __restrict__ h,
    const float* __restrict__ Wa, const float* __restrict__ ba,
    const float* __restrict__ node, const float* __restrict__ gamma,
    const float* __restrict__ beta, float* __restrict__ out)
{
    __shared__ __align__(16) float s_aj[NN * 32];   // 32 KB chunk buffer; aliased as s_part later
    __shared__ __align__(16) float s_w[NN * IT];    // transposed w: [j][r]
    __shared__ __align__(16) float s_m[DD * IT];    // transposed msg: [k][r]
    __shared__ float s_red[IT][4];
    __shared__ float s_red2[IT][2][2];

    int tid = threadIdx.x;
    int b  = blockIdx.x / (NN / IT);
    int i0 = (blockIdx.x % (NN / IT)) * IT;
    int j = tid;

    // ---- Phase 1: edge scores; per-lane state for 2 rows
    const float2* rel2 = (const float2*)rel;
    float rx[IT], ry[IT], dsv[IT], sc[IT];
    int msk[IT];
    float be2v = be2[0];
    #pragma unroll
    for (int r = 0; r < IT; ++r) {
        float2 rp = rel2[(size_t)(b * NN + i0 + r) * NN + j];
        rx[r] = rp.x; ry[r] = rp.y;
        dsv[r] = sqrtf(rp.x * rp.x + rp.y * rp.y);
        msk[r] = adj[(size_t)(b * NN + i0 + r) * NN + j];
        sc[r] = be2v;
    }
    const float* TI = ti + (size_t)(b * NN + i0) * DD;          // uniform base
    const float* W0 = We1 + (size_t)(2 * DD + 0) * DD;
    const float* W1 = We1 + (size_t)(2 * DD + 1) * DD;
    const float* W2 = We1 + (size_t)(2 * DD + 2) * DD;

    for (int dc = 0; dc < DD; dc += 32) {
        __syncthreads();
        // stage aj[:, dc:dc+32] with XOR-swizzled float4 slots (aligned ds_write_b128)
        #pragma unroll
        for (int it = 0; it < 8; ++it) {
            int idx = tid + it * 256;
            int rr = idx >> 3, g = idx & 7;
            float4 v = *(const float4*)&ajp[(size_t)(b * NN + rr) * DD + dc + (g << 2)];
            *(float4*)&s_aj[rr * 32 + ((g ^ (rr & 7)) << 2)] = v;
        }
        __syncthreads();
        #pragma unroll
        for (int g = 0; g < 8; ++g) {
            float4 a = *(const float4*)&s_aj[j * 32 + ((g ^ (j & 7)) << 2)];
            int dd = dc + (g << 2);
            float4 w0 = *(const float4*)&W0[dd];    // uniform -> s_load_dwordx4
            float4 w1 = *(const float4*)&W1[dd];
            float4 w2 = *(const float4*)&W2[dd];
            float4 e2 = *(const float4*)&We2[dd];
            #pragma unroll
            for (int r = 0; r < IT; ++r) {
                float4 t = *(const float4*)&TI[r * DD + dd];    // uniform -> s_load
                float v0;
                v0 = fmaf(rx[r], w0.x, t.x + a.x); v0 = fmaf(ry[r], w1.x, v0); v0 = fmaf(dsv[r], w2.x, v0);
                sc[r] = fmaf(fmaxf(v0, 0.f), e2.x, sc[r]);
                v0 = fmaf(rx[r], w0.y, t.y + a.y); v0 = fmaf(ry[r], w1.y, v0); v0 = fmaf(dsv[r], w2.y, v0);
                sc[r] = fmaf(fmaxf(v0, 0.f), e2.y, sc[r]);
                v0 = fmaf(rx[r], w0.z, t.z + a.z); v0 = fmaf(ry[r], w1.z, v0); v0 = fmaf(dsv[r], w2.z, v0);
                sc[r] = fmaf(fmaxf(v0, 0.f), e2.z, sc[r]);
                v0 = fmaf(rx[r], w0.w, t.w + a.w); v0 = fmaf(ry[r], w1.w, v0); v0 = fmaf(dsv[r], w2.w, v0);
                sc[r] = fmaf(fmaxf(v0, 0.f), e2.w, sc[r]);
            }
        }
    }
    #pragma unroll
    for (int r = 0; r < IT; ++r) if (msk[r] == 0) sc[r] = -3.0e38f;

    // ---- Phase 2: masked softmax across j (4 waves)
    int wave = tid >> 6, lane = tid & 63;
    float e[IT];
    {
        float m0 = sc[0], m1 = sc[1];
        for (int off = 32; off > 0; off >>= 1) {
            m0 = fmaxf(m0, __shfl_xor(m0, off));
            m1 = fmaxf(m1, __shfl_xor(m1, off));
        }
        if (lane == 0) { s_red[0][wave] = m0; s_red[1][wave] = m1; }
    }
    __syncthreads();
    #pragma unroll
    for (int r = 0; r < IT; ++r) {
        float M = fmaxf(fmaxf(s_red[r][0], s_red[r][1]), fmaxf(s_red[r][2], s_red[r][3]));
        e[r] = (msk[r] == 0) ? 0.f : __expf(sc[r] - M);
    }
    __syncthreads();
    {
        float s0 = e[0], s1 = e[1];
        for (int off = 32; off > 0; off >>= 1) {
            s0 += __shfl_xor(s0, off);
            s1 += __shfl_xor(s1, off);
        }
        if (lane == 0) { s_red[0][wave] = s0; s_red[1][wave] = s1; }
    }
    __syncthreads();
    {
        float S0 = s_red[0][0] + s_red[0][1] + s_red[0][2] + s_red[0][3];
        float S1 = s_red[1][0] + s_red[1][1] + s_red[1][2] + s_red[1][3];
        float w0 = e[0] * __builtin_amdgcn_rcpf(S0);
        float w1 = e[1] * __builtin_amdgcn_rcpf(S1);
        *(float2*)&s_w[j * 2] = make_float2(w0, w1);   // transposed store
    }
    __syncthreads();

    // ---- Phase 3: msg = w@h via slice partials. Thread: g3=tid&31 (d4-group), sl=tid>>5 (j-slice)
    float* s_part = s_aj;                              // alias (aj chunks dead)
    int g3 = tid & 31, sl = tid >> 5;
    {
        const float* hb = h + (size_t)b * NN * DD;
        float4 acc0 = make_float4(0.f, 0.f, 0.f, 0.f);
        float4 acc1 = make_float4(0.f, 0.f, 0.f, 0.f);
        for (int q = 0; q < 32; ++q) {
            int jj = (sl << 5) + q;
            float4 hv = *(const float4*)&hb[(size_t)jj * DD + (g3 << 2)];
            float2 wv = *(const float2*)&s_w[jj * 2];
            acc0.x = fmaf(wv.x, hv.x, acc0.x); acc0.y = fmaf(wv.x, hv.y, acc0.y);
            acc0.z = fmaf(wv.x, hv.z, acc0.z); acc0.w = fmaf(wv.x, hv.w, acc0.w);
            acc1.x = fmaf(wv.y, hv.x, acc1.x); acc1.y = fmaf(wv.y, hv.y, acc1.y);
            acc1.z = fmaf(wv.y, hv.z, acc1.z); acc1.w = fmaf(wv.y, hv.w, acc1.w);
        }
        __syncthreads();
        *(float4*)&s_part[(((sl << 5) + g3) * 2 + 0) << 2] = acc0;
        *(float4*)&s_part[(((sl << 5) + g3) * 2 + 1) << 2] = acc1;
    }
    __syncthreads();
    {
        int r = tid >> 7, d = tid & 127;               // 256 outputs, one per thread
        float s = 0.f;
        #pragma unroll
        for (int s2 = 0; s2 < 8; ++s2)
            s += s_part[((((s2 << 5) + (d >> 2)) * 2 + r) << 2) + (d & 3)];
        s_m[d * 2 + r] = s;                            // transposed msg
    }
    __syncthreads();

    // ---- Phase 4: agg = relu(msg@Wa+ba). Thread: g4=tid&31 (d4-group), ks=tid>>5 (k-slice of 16)
    {
        float4 ac0 = make_float4(0.f, 0.f, 0.f, 0.f);
        float4 ac1 = make_float4(0.f, 0.f, 0.f, 0.f);
        int ks = sl;
        for (int q = 0; q < 16; ++q) {
            int k = (ks << 4) + q;
            float4 wa = *(const float4*)&Wa[(size_t)k * DD + (g3 << 2)];
            float2 mv = *(const float2*)&s_m[k * 2];
            ac0.x = fmaf(mv.x, wa.x, ac0.x); ac0.y = fmaf(mv.x, wa.y, ac0.y);
            ac0.z = fmaf(mv.x, wa.z, ac0.z); ac0.w = fmaf(mv.x, wa.w, ac0.w);
            ac1.x = fmaf(mv.y, wa.x, ac1.x); ac1.y = fmaf(mv.y, wa.y, ac1.y);
            ac1.z = fmaf(mv.y, wa.z, ac1.z); ac1.w = fmaf(mv.y, wa.w, ac1.w);
        }
        __syncthreads();
        *(float4*)&s_part[(((ks << 5) + g3) * 2 + 0) << 2] = ac0;
        *(float4*)&s_part[(((ks << 5) + g3) * 2 + 1) << 2] = ac1;
    }
    __syncthreads();

    // ---- Phase 5: reduce, bias+relu, residual, LayerNorm
    {
        int r = tid >> 7, d = tid & 127;
        float agg = 0.f;
        #pragma unroll
        for (int s2 = 0; s2 < 8; ++s2)
            agg += s_part[((((s2 << 5) + (d >> 2)) * 2 + r) << 2) + (d & 3)];
        float x = node[(size_t)(b * NN + i0 + r) * DD + d] + fmaxf(agg + ba[d], 0.f);
        int wh = (tid >> 6) & 1;
        float s1 = x, s2v = x * x;
        for (int off = 32; off > 0; off >>= 1) {
            s1 += __shfl_xor(s1, off);
            s2v += __shfl_xor(s2v, off);
        }
        if (lane == 0) { s_red2[r][wh][0] = s1; s_red2[r][wh][1] = s2v; }
        __syncthreads();
        float t1 = s_red2[r][0][0] + s_red2[r][1][0];
        float t2 = s_red2[r][0][1] + s_red2[r][1][1];
        float mu  = t1 * (1.0f / DD);
        float var = t2 * (1.0f / DD) - mu * mu;
        float inv = rsqrtf(var + 1e-5f);
        out[(size_t)(b * NN + i0 + r) * DD + d] = (x - mu) * inv * gamma[d] + beta[d];
    }
}

extern "C" void kernel_launch(void* const* d_in, const int* in_sizes, int n_in,
                              void* d_out, int out_size, void* d_ws, size_t ws_size,
                              hipStream_t stream) {
    const float* node = (const float*)d_in[0];
    const int*   adj  = (const int*)d_in[1];
    const float* rel  = (const float*)d_in[2];
    const float* Wn   = (const float*)d_in[3];
    const float* bn   = (const float*)d_in[4];
    const float* We1  = (const float*)d_in[5];
    const float* be1  = (const float*)d_in[6];
    const float* We2  = (const float*)d_in[7];
    const float* be2  = (const float*)d_in[8];
    const float* Wa   = (const float*)d_in[9];
    const float* ba   = (const float*)d_in[10];
    const float* gamma = (const float*)d_in[11];
    const float* beta  = (const float*)d_in[12];
    float* out = (float*)d_out;

    float* ws  = (float*)d_ws;
    const int ROWS = BB * NN * DD;          // 262144
    float* h   = ws;
    float* ti  = ws + ROWS;
    float* aj  = ws + 2 * ROWS;

    prep_kernel<<<BB * NN / PR, 256, 0, stream>>>(node, Wn, bn, We1, be1, h, ti, aj);
    edge_kernel<<<BB * NN / IT, 256, 0, stream>>>(ti, aj, rel, adj, We1, We2, be2,
                                                  h, Wa, ba, node, gamma, beta, out);
}